// Round 10
// baseline (207.769 us; speedup 1.0000x reference)
//
#include <hip/hip_runtime.h>
#include <math.h>

#define BDIM 64
#define NN   2048
#define EE   8192
#define LL   50
#define DD   128
#define RR   5
#define NBASES 4
#define H3   192
#define RECCAP 1024
#define KDIM 768          // 128 (root) + 5*128 (relations)
#define GR   8            // rows per gemm block (wave w gathers+owns rows 2w,2w+1)

__device__ __forceinline__ void fma4(float4& a, float s, const float4& w) {
    a.x = fmaf(s, w.x, a.x); a.y = fmaf(s, w.y, a.y);
    a.z = fmaf(s, w.z, a.z); a.w = fmaf(s, w.w, a.w);
}

// ---------------------------------------------------------------------------
// K1: all small precomputes in one launch.
//   blocks [0,384):   Wcat[768][128] = [root_w ; W_r = comp.bases]
//   blocks [384,512): A[i][j] = wq[i]·wk[j]
//   block  512:       va/vf = wv·attn_w / wv·fc_w
// ---------------------------------------------------------------------------
__global__ __launch_bounds__(256) void precompute_all(
        const float* __restrict__ bases, const float* __restrict__ comp,
        const float* __restrict__ root_w, const float* __restrict__ wq,
        const float* __restrict__ wk, const float* __restrict__ wv,
        const float* __restrict__ attn_w, const float* __restrict__ fc_w,
        float* __restrict__ Wcat, float* __restrict__ A,
        float* __restrict__ va, float* __restrict__ vf) {
    int blk = blockIdx.x, t = threadIdx.x;
    if (blk < 384) {
        int idx = blk * 256 + t;              // < 98304 = 768*128
        int k = idx >> 7, o = idx & 127;
        if (k < DD) {
            Wcat[idx] = root_w[idx];
        } else {
            int r = (k - DD) >> 7, i = (k - DD) & 127;
            float s = 0.f;
#pragma unroll
            for (int bb = 0; bb < NBASES; ++bb)
                s += comp[r * NBASES + bb] * bases[bb * DD * DD + i * DD + o];
            Wcat[idx] = s;
        }
    } else if (blk < 512) {
        int i = blk - 384;
        __shared__ float wqs[H3];
        if (t < H3) wqs[t] = wq[i * H3 + t];
        __syncthreads();
        if (t < DD) {
            const float4* wkr = (const float4*)(wk + t * H3);
            float s = 0.f;
#pragma unroll
            for (int d4 = 0; d4 < H3 / 4; ++d4) {
                float4 v = wkr[d4];
                s += wqs[4*d4]*v.x + wqs[4*d4+1]*v.y + wqs[4*d4+2]*v.z + wqs[4*d4+3]*v.w;
            }
            A[i * DD + t] = s;
        }
    } else {
        if (t < DD) {
            const float4* wr = (const float4*)(wv + t * H3);
            float a = 0.f, f = 0.f;
#pragma unroll
            for (int d4 = 0; d4 < H3 / 4; ++d4) {
                float4 v = wr[d4];
                a += v.x*attn_w[4*d4] + v.y*attn_w[4*d4+1] + v.z*attn_w[4*d4+2] + v.w*attn_w[4*d4+3];
                f += v.x*fc_w[4*d4] + v.y*fc_w[4*d4+1] + v.z*fc_w[4*d4+2] + v.w*fc_w[4*d4+3];
            }
            va[t] = a; vf[t] = f;
        }
    }
}

// ---------------------------------------------------------------------------
// K2: matchseg — one block per batch. Scan edges once, bucket matches by
// (l,r) with an LDS prefix sum -> segmented recbuf2 + segoff[b][251].
// ---------------------------------------------------------------------------
__global__ __launch_bounds__(512) void matchseg(const int* __restrict__ edge_index,
                                                const int* __restrict__ edge_type,
                                                const int* __restrict__ sent_ids,
                                                int* __restrict__ rep,
                                                int* __restrict__ segoff,
                                                int* __restrict__ recbuf2) {
    int b = blockIdx.x, t = threadIdx.x;
    __shared__ int mark[NN];
    __shared__ int scnt[LL * RR];
    __shared__ int soff[LL * RR + 1];
    __shared__ int scan[256];
    __shared__ int recs[RECCAP];
    __shared__ int lcnt;

    for (int i = t; i < NN; i += 512) mark[i] = -1;
    if (t < LL * RR) scnt[t] = 0;
    if (t == 0) lcnt = 0;
    __syncthreads();
    const int* sb = sent_ids + b * LL;
    if (t < LL) mark[sb[t]] = t;            // duplicates: arbitrary but consistent winner
    __syncthreads();
    if (t < LL) rep[b * LL + t] = mark[sb[t]];

    const int* src_arr = edge_index + (size_t)b * 2 * EE;
    const int* tgt_arr = src_arr + EE;
    const int* et_arr  = edge_type + (size_t)b * EE;
    const int4* tgt4 = (const int4*)tgt_arr;
    for (int i4 = t; i4 < EE / 4; i4 += 512) {
        int4 v = tgt4[i4];
        int e0 = 4 * i4;
        int lv[4] = {mark[v.x], mark[v.y], mark[v.z], mark[v.w]};
#pragma unroll
        for (int k = 0; k < 4; ++k) {
            int l = lv[k];
            if (l >= 0) {
                int e = e0 + k;
                int r = et_arr[e];
                int s = src_arr[e];
                int pos = atomicAdd(&lcnt, 1);
                if (pos < RECCAP) {
                    recs[pos] = (l << 14) | (r << 11) | s;
                    atomicAdd(&scnt[l * RR + r], 1);
                }
            }
        }
    }
    __syncthreads();
    // inclusive scan of scnt[0..249] over 256 lanes (Hillis-Steele)
    if (t < 256) scan[t] = (t < LL * RR) ? scnt[t] : 0;
    __syncthreads();
    for (int off = 1; off < 256; off <<= 1) {
        int v = 0;
        if (t < 256 && t >= off) v = scan[t - off];
        __syncthreads();
        if (t < 256) scan[t] += v;
        __syncthreads();
    }
    if (t == 0) soff[0] = 0;
    if (t < LL * RR) soff[t + 1] = scan[t];
    if (t < LL * RR) scnt[t] = 0;           // reset cursors
    __syncthreads();
    if (t <= LL * RR) segoff[b * (LL * RR + 1) + t] = soff[t];
    int nm = (lcnt < RECCAP) ? lcnt : RECCAP;
    for (int i = t; i < nm; i += 512) {
        int rc = recs[i];
        int key = (rc >> 14) * RR + ((rc >> 11) & 7);
        int pos = soff[key] + atomicAdd(&scnt[key], 1);
        recbuf2[b * RECCAP + pos] = rc;
    }
}

// ---------------------------------------------------------------------------
// K3: gemm_fused8 — 400 blocks x 256 threads, 8 rows x 128 cols per block.
// Phase A: wave w gathers rows 2w,2w+1 (xnode + per-relation means) into Us.
// Phase B: X = Us @ Wcat + root_b; thread = 1 row x 4 cols; weights from L2.
// Phase C: XA = X @ A (same shape); p/q wave reductions.
// Rows 2w,2w+1 are gathered, computed, and reduced entirely by wave w ->
// single barrier (vas/vfs staging only). 29 KB LDS -> high co-residency.
// ---------------------------------------------------------------------------
__global__ __launch_bounds__(256) void gemm_fused8(const float* __restrict__ emb,
                                                   const float* __restrict__ Wcat,
                                                   const float* __restrict__ A,
                                                   const float* __restrict__ root_b,
                                                   const float* __restrict__ va,
                                                   const float* __restrict__ vf,
                                                   const int* __restrict__ node_ids,
                                                   const int* __restrict__ sent_ids,
                                                   const int* __restrict__ rep,
                                                   const int* __restrict__ segoff,
                                                   const int* __restrict__ recbuf2,
                                                   float* __restrict__ Xws,
                                                   float* __restrict__ XAws,
                                                   float* __restrict__ pv,
                                                   float* __restrict__ qv) {
    __shared__ float Us[GR][KDIM];     // 24 KB
    __shared__ float Xs[GR][DD];       // 4 KB
    __shared__ float vas[DD], vfs[DD];

    int t = threadIdx.x;
    int w = t >> 6, lane = t & 63;
    int row0 = blockIdx.x * GR;

    // --- Phase A: wave w gathers rows 2w and 2w+1
#pragma unroll
    for (int rr = 0; rr < 2; ++rr) {
        int lrow = 2 * w + rr;
        int bl = row0 + lrow;
        int b  = bl / LL;
        const int* nid = node_ids + (size_t)b * NN;
        int myrep = rep[bl];
        const int* so = segoff + b * (LL * RR + 1) + myrep * RR;
        const int* rb = recbuf2 + b * RECCAP;
        int nrow = nid[sent_ids[bl]];
        Us[lrow][lane]      = emb[(size_t)nrow * DD + lane];
        Us[lrow][lane + 64] = emb[(size_t)nrow * DD + 64 + lane];
#pragma unroll
        for (int r = 0; r < RR; ++r) {
            int s0 = so[r], s1 = so[r + 1];
            float a0 = 0.f, a1 = 0.f;
            for (int j = s0; j < s1; ++j) {
                int s = rb[j] & 2047;
                int rw = nid[s];
                a0 += emb[(size_t)rw * DD + lane];
                a1 += emb[(size_t)rw * DD + 64 + lane];
            }
            float inv = (s1 > s0) ? 1.f / (float)(s1 - s0) : 0.f;
            Us[lrow][DD + r * DD + lane]      = a0 * inv;
            Us[lrow][DD + r * DD + 64 + lane] = a1 * inv;
        }
    }
    if (t < DD) { vas[t] = va[t]; vfs[t] = vf[t]; }
    __syncthreads();

    // --- Phase B: X = Us @ Wcat + root_b (thread: row rg, cols 4cg..4cg+3)
    int cg = t & 31, rg = t >> 5;      // rg 0..7; wave w holds rg 2w, 2w+1
    int bl_r = row0 + rg;
    float4 acc = *(const float4*)(root_b + 4 * cg);
    const float4* Wc4 = (const float4*)Wcat;
    const float4* u4p = (const float4*)Us[rg];
#pragma unroll 2
    for (int k4 = 0; k4 < KDIM / 4; ++k4) {
        float4 u = u4p[k4];
        int k = 4 * k4;
        float4 w0 = Wc4[(k + 0) * 32 + cg];
        float4 w1 = Wc4[(k + 1) * 32 + cg];
        float4 w2 = Wc4[(k + 2) * 32 + cg];
        float4 w3 = Wc4[(k + 3) * 32 + cg];
        fma4(acc, u.x, w0);
        fma4(acc, u.y, w1);
        fma4(acc, u.z, w2);
        fma4(acc, u.w, w3);
    }
    *(float4*)&Xs[rg][4 * cg] = acc;
    *(float4*)(Xws + (size_t)bl_r * DD + 4 * cg) = acc;
    // Xs[rg] written and read only within wave w — in-wave DS ordering suffices.

    // --- Phase C: XA = X @ A
    float4 z = {0.f, 0.f, 0.f, 0.f};
    const float4* A4 = (const float4*)A;
    const float4* x4p = (const float4*)Xs[rg];
#pragma unroll 2
    for (int k4 = 0; k4 < DD / 4; ++k4) {
        float4 x = x4p[k4];
        int k = 4 * k4;
        float4 a0 = A4[(k + 0) * 32 + cg];
        float4 a1 = A4[(k + 1) * 32 + cg];
        float4 a2 = A4[(k + 2) * 32 + cg];
        float4 a3 = A4[(k + 3) * 32 + cg];
        fma4(z, x.x, a0);
        fma4(z, x.y, a1);
        fma4(z, x.z, a2);
        fma4(z, x.w, a3);
    }
    *(float4*)(XAws + (size_t)bl_r * DD + 4 * cg) = z;

    // --- p/q: wave w reduces its own rows 2w, 2w+1 (written by this wave)
#pragma unroll
    for (int rr = 0; rr < 2; ++rr) {
        int m = 2 * w + rr;
        float xv0 = Xs[m][lane], xv1 = Xs[m][lane + 64];
        float pp = xv0 * vas[lane] + xv1 * vas[lane + 64];
        float qq = xv0 * vfs[lane] + xv1 * vfs[lane + 64];
#pragma unroll
        for (int off = 32; off; off >>= 1) {
            pp += __shfl_xor(pp, off);
            qq += __shfl_xor(qq, off);
        }
        if (lane == 0) { pv[row0 + m] = pp; qv[row0 + m] = qq; }
    }
}

// ---------------------------------------------------------------------------
// K4: attn_batch — one block (4 waves) per batch. X staged transposed as
// float4 (XT4[k][m]), lane m owns score column m. Wave w handles rows
// l = w, w+4, ... Softmax + pooled product in-wave; out[b] written directly.
// ---------------------------------------------------------------------------
__global__ __launch_bounds__(256) void attn_batch(const float* __restrict__ Xws,
                                                  const float* __restrict__ XAws,
                                                  const float* __restrict__ pv,
                                                  const float* __restrict__ qv,
                                                  const float* __restrict__ attn_b,
                                                  const float* __restrict__ fc_b,
                                                  float* __restrict__ out) {
    __shared__ float4 XT4[32][64];    // XT4[k][m] = X[m][4k..4k+3]; 32 KB
    __shared__ float4 XA4[LL][32];    // XA rows as float4; 25.6 KB
    __shared__ float pvs[64], qvs[64];
    __shared__ float partial[4];

    int b = blockIdx.x, t = threadIdx.x;
    int w = t >> 6, lane = t & 63;

    const float4* Xb4  = (const float4*)(Xws  + (size_t)b * LL * DD);
    const float4* XAb4 = (const float4*)(XAws + (size_t)b * LL * DD);
    for (int idx = t; idx < LL * 32; idx += 256) {
        int m = idx >> 5, k = idx & 31;
        XT4[k][m] = Xb4[idx];                 // coalesced read, scattered LDS write
        ((float4*)XA4)[idx] = XAb4[idx];
    }
    if (t < 64) {
        pvs[t] = (t < LL) ? pv[b * LL + t] : 0.f;
        qvs[t] = (t < LL) ? qv[b * LL + t] : 0.f;
    }
    __syncthreads();

    const float scale = 0.07216878364870322f;  // 1/sqrt(192)
    float ab = attn_b[0];
    float local = 0.f;
    for (int l = w; l < LL; l += 4) {
        float s = 0.f;
#pragma unroll
        for (int kk = 0; kk < 32; ++kk) {
            float4 xa = XA4[l][kk];           // broadcast
            float4 xt = XT4[kk][lane];        // conflict-free b128
            s = fmaf(xa.x, xt.x, s);
            s = fmaf(xa.y, xt.y, s);
            s = fmaf(xa.z, xt.z, s);
            s = fmaf(xa.w, xt.w, s);
        }
        s *= scale;
        float sval = (lane < LL) ? s : -INFINITY;
        float mx = sval;
#pragma unroll
        for (int off = 32; off; off >>= 1) mx = fmaxf(mx, __shfl_xor(mx, off));
        float e = (lane < LL) ? __expf(sval - mx) : 0.f;
        float sum = e, pa = e * pvs[lane], qa = e * qvs[lane];
#pragma unroll
        for (int off = 32; off; off >>= 1) {
            sum += __shfl_xor(sum, off);
            pa  += __shfl_xor(pa, off);
            qa  += __shfl_xor(qa, off);
        }
        float inv = 1.f / sum;
        local += (pa * inv + ab) * (qa * inv);
    }
    if (lane == 0) partial[w] = local;
    __syncthreads();
    if (t == 0) {
        float s = partial[0] + partial[1] + partial[2] + partial[3];
        out[b] = 1.f / (1.f + expf(-(s + fc_b[0])));
    }
}

// ---------------------------------------------------------------------------
extern "C" void kernel_launch(void* const* d_in, const int* in_sizes, int n_in,
                              void* d_out, int out_size, void* d_ws, size_t ws_size,
                              hipStream_t stream) {
    const float* emb     = (const float*)d_in[0];
    const float* bases   = (const float*)d_in[1];
    const float* comp    = (const float*)d_in[2];
    const float* root_w  = (const float*)d_in[3];
    const float* root_b  = (const float*)d_in[4];
    const float* wq      = (const float*)d_in[5];
    const float* wk      = (const float*)d_in[6];
    const float* wv      = (const float*)d_in[7];
    const float* attn_w  = (const float*)d_in[8];
    const float* attn_b  = (const float*)d_in[9];
    const float* fc_w    = (const float*)d_in[10];
    const float* fc_b    = (const float*)d_in[11];
    const int* node_ids  = (const int*)d_in[12];
    const int* edge_index= (const int*)d_in[13];
    const int* edge_type = (const int*)d_in[14];
    const int* sent_ids  = (const int*)d_in[15];
    float* out = (float*)d_out;

    float* ws = (float*)d_ws;
    float* Wcat = ws;                         // 98304
    float* A    = ws + 98304;                 // 16384
    float* va   = ws + 114688;                // 128
    float* vf   = ws + 114816;                // 128
    float* pv   = ws + 114944;                // 3200
    float* qv   = ws + 118144;                // 3200
    float* Xws  = ws + 121344;                // 409600
    float* XAws = ws + 530944;                // 409600
    int* rep     = (int*)(ws + 940544);       // 3200
    int* segoff  = (int*)(ws + 943744);       // 64*251 = 16064
    int* recbuf2 = (int*)(ws + 959808);       // 65536
    // total ~1.03M elems ≈ 4.1 MiB

    hipLaunchKernelGGL(precompute_all, dim3(513), dim3(256), 0, stream,
                       bases, comp, root_w, wq, wk, wv, attn_w, fc_w,
                       Wcat, A, va, vf);
    hipLaunchKernelGGL(matchseg, dim3(BDIM), dim3(512), 0, stream,
                       edge_index, edge_type, sent_ids, rep, segoff, recbuf2);
    hipLaunchKernelGGL(gemm_fused8, dim3(BDIM * LL / GR), dim3(256), 0, stream,
                       emb, Wcat, A, root_b, va, vf, node_ids, sent_ids,
                       rep, segoff, recbuf2, Xws, XAws, pv, qv);
    hipLaunchKernelGGL(attn_batch, dim3(BDIM), dim3(256), 0, stream,
                       Xws, XAws, pv, qv, attn_b, fc_b, out);
}

// Round 11
// 184.784 us; speedup vs baseline: 1.1244x; 1.1244x over previous
//
#include <hip/hip_runtime.h>
#include <math.h>

#define BDIM 64
#define NN   2048
#define EE   8192
#define LL   50
#define DD   128
#define RR   5
#define NBASES 4
#define H3   192
#define RECCAP 1024
#define MT   16           // rows per gemm block
#define NS   3            // K slices (256 each): [root|r0], [r1|r2], [r3|r4]
#define SK   256          // K per slice
#define KC   32           // K chunk staged in LDS

__device__ __forceinline__ void fma4(float4& a, float s, const float4& w) {
    a.x = fmaf(s, w.x, a.x); a.y = fmaf(s, w.y, a.y);
    a.z = fmaf(s, w.z, a.z); a.w = fmaf(s, w.w, a.w);
}

// ---------------------------------------------------------------------------
// K1a: W2 cols 0..127 = [root_w ; W_r] (row stride 256), A, va/vf, bias2[0:128]
// ---------------------------------------------------------------------------
__global__ __launch_bounds__(256) void precompute_base(
        const float* __restrict__ bases, const float* __restrict__ comp,
        const float* __restrict__ root_w, const float* __restrict__ root_b,
        const float* __restrict__ wq, const float* __restrict__ wk,
        const float* __restrict__ wv, const float* __restrict__ attn_w,
        const float* __restrict__ fc_w,
        float* __restrict__ W2, float* __restrict__ A,
        float* __restrict__ va, float* __restrict__ vf,
        float* __restrict__ bias2) {
    int blk = blockIdx.x, t = threadIdx.x;
    if (blk < 384) {
        int idx = blk * 256 + t;              // < 98304 = 768*128
        int k = idx >> 7, o = idx & 127;
        float s;
        if (k < DD) {
            s = root_w[idx];
        } else {
            int r = (k - DD) >> 7, i = (k - DD) & 127;
            s = 0.f;
#pragma unroll
            for (int bb = 0; bb < NBASES; ++bb)
                s += comp[r * NBASES + bb] * bases[bb * DD * DD + i * DD + o];
        }
        W2[(size_t)k * 256 + o] = s;
    } else if (blk < 512) {
        int i = blk - 384;
        __shared__ float wqs[H3];
        if (t < H3) wqs[t] = wq[i * H3 + t];
        __syncthreads();
        if (t < DD) {
            const float4* wkr = (const float4*)(wk + t * H3);
            float s = 0.f;
#pragma unroll
            for (int d4 = 0; d4 < H3 / 4; ++d4) {
                float4 v = wkr[d4];
                s += wqs[4*d4]*v.x + wqs[4*d4+1]*v.y + wqs[4*d4+2]*v.z + wqs[4*d4+3]*v.w;
            }
            A[i * DD + t] = s;
        }
    } else {
        if (t < DD) {
            const float4* wr = (const float4*)(wv + t * H3);
            float a = 0.f, f = 0.f;
#pragma unroll
            for (int d4 = 0; d4 < H3 / 4; ++d4) {
                float4 v = wr[d4];
                a += v.x*attn_w[4*d4] + v.y*attn_w[4*d4+1] + v.z*attn_w[4*d4+2] + v.w*attn_w[4*d4+3];
                f += v.x*fc_w[4*d4] + v.y*fc_w[4*d4+1] + v.z*fc_w[4*d4+2] + v.w*fc_w[4*d4+3];
            }
            va[t] = a; vf[t] = f;
            bias2[t] = root_b[t];
        }
    }
}

// ---------------------------------------------------------------------------
// K1b: W2 cols 128..255 = Wcat @ A (blocks 0..767: row i); block 768:
// bias2[128+j] = root_b @ A.
// ---------------------------------------------------------------------------
__global__ __launch_bounds__(128) void precompute_fold(
        const float* __restrict__ A, const float* __restrict__ root_b,
        float* __restrict__ W2, float* __restrict__ bias2) {
    int i = blockIdx.x, j = threadIdx.x;
    __shared__ float wrow[DD];
    if (i < 768) {
        wrow[j] = W2[(size_t)i * 256 + j];
        __syncthreads();
        float s = 0.f;
        for (int k = 0; k < DD; ++k) s = fmaf(wrow[k], A[k * DD + j], s);
        W2[(size_t)i * 256 + 128 + j] = s;
    } else {
        wrow[j] = root_b[j];
        __syncthreads();
        float s = 0.f;
        for (int k = 0; k < DD; ++k) s = fmaf(wrow[k], A[k * DD + j], s);
        bias2[128 + j] = s;
    }
}

// ---------------------------------------------------------------------------
// K2: matchseg — one block per batch. Scan edges once, bucket matches by
// (l,r) with an LDS prefix sum -> segmented recbuf2 + segoff[b][251].
// ---------------------------------------------------------------------------
__global__ __launch_bounds__(512) void matchseg(const int* __restrict__ edge_index,
                                                const int* __restrict__ edge_type,
                                                const int* __restrict__ sent_ids,
                                                int* __restrict__ rep,
                                                int* __restrict__ segoff,
                                                int* __restrict__ recbuf2) {
    int b = blockIdx.x, t = threadIdx.x;
    __shared__ int mark[NN];
    __shared__ int scnt[LL * RR];
    __shared__ int soff[LL * RR + 1];
    __shared__ int scan[256];
    __shared__ int recs[RECCAP];
    __shared__ int lcnt;

    for (int i = t; i < NN; i += 512) mark[i] = -1;
    if (t < LL * RR) scnt[t] = 0;
    if (t == 0) lcnt = 0;
    __syncthreads();
    const int* sb = sent_ids + b * LL;
    if (t < LL) mark[sb[t]] = t;            // duplicates: consistent winner
    __syncthreads();
    if (t < LL) rep[b * LL + t] = mark[sb[t]];

    const int* src_arr = edge_index + (size_t)b * 2 * EE;
    const int* tgt_arr = src_arr + EE;
    const int* et_arr  = edge_type + (size_t)b * EE;
    const int4* tgt4 = (const int4*)tgt_arr;
    for (int i4 = t; i4 < EE / 4; i4 += 512) {
        int4 v = tgt4[i4];
        int e0 = 4 * i4;
        int lv[4] = {mark[v.x], mark[v.y], mark[v.z], mark[v.w]};
#pragma unroll
        for (int k = 0; k < 4; ++k) {
            int l = lv[k];
            if (l >= 0) {
                int e = e0 + k;
                int r = et_arr[e];
                int s = src_arr[e];
                int pos = atomicAdd(&lcnt, 1);
                if (pos < RECCAP) {
                    recs[pos] = (l << 14) | (r << 11) | s;
                    atomicAdd(&scnt[l * RR + r], 1);
                }
            }
        }
    }
    __syncthreads();
    if (t < 256) scan[t] = (t < LL * RR) ? scnt[t] : 0;
    __syncthreads();
    for (int off = 1; off < 256; off <<= 1) {
        int v = 0;
        if (t < 256 && t >= off) v = scan[t - off];
        __syncthreads();
        if (t < 256) scan[t] += v;
        __syncthreads();
    }
    if (t == 0) soff[0] = 0;
    if (t < LL * RR) soff[t + 1] = scan[t];
    if (t < LL * RR) scnt[t] = 0;
    __syncthreads();
    if (t <= LL * RR) segoff[b * (LL * RR + 1) + t] = soff[t];
    int nm = (lcnt < RECCAP) ? lcnt : RECCAP;
    for (int i = t; i < nm; i += 512) {
        int rc = recs[i];
        int key = (rc >> 14) * RR + ((rc >> 11) & 7);
        int pos = soff[key] + atomicAdd(&scnt[key], 1);
        recbuf2[b * RECCAP + pos] = rc;
    }
}

// ---------------------------------------------------------------------------
// K3: gemm_ksplit — 600 blocks (200 m-tiles x 3 K-slices), 256 threads.
// Phase A: gather this slice's 2 sub-slices into Uc[16][256] (wave: 4 rows).
// Phase B: Xpart[ks] += Uc @ W2[slice rows], chunked through Wb[32][256].
// Thread = 4 rows x 4 cols; LDS 49 KB -> 3 blocks/CU; all 600 co-resident.
// ---------------------------------------------------------------------------
__global__ __launch_bounds__(256) void gemm_ksplit(const float* __restrict__ emb,
                                                   const float* __restrict__ W2,
                                                   const int* __restrict__ node_ids,
                                                   const int* __restrict__ sent_ids,
                                                   const int* __restrict__ rep,
                                                   const int* __restrict__ segoff,
                                                   const int* __restrict__ recbuf2,
                                                   float* __restrict__ Xpart) {
    __shared__ float Uc[MT][SK];       // 16 KB
    __shared__ float Wb[KC][256];      // 32 KB

    int t = threadIdx.x;
    int w = t >> 6, lane = t & 63;
    int mt = blockIdx.x % 200;
    int ks = blockIdx.x / 200;
    int m0 = mt * MT;

    // --- Phase A: wave w gathers rows 4w..4w+3, sub-slices {2ks-1, 2ks}
#pragma unroll
    for (int rr = 0; rr < 4; ++rr) {
        int row = 4 * w + rr;
        int bl = m0 + row;
        int b  = bl / LL;
        const int* nid = node_ids + (size_t)b * NN;
        int myrep = rep[bl];
        const int* so = segoff + b * (LL * RR + 1) + myrep * RR;
        const int* rb = recbuf2 + b * RECCAP;
#pragma unroll
        for (int s = 0; s < 2; ++s) {
            int kind = ks * 2 + s - 1;     // -1 = root, 0..4 = relation
            float u0, u1;
            if (kind < 0) {
                int nrow = nid[sent_ids[bl]];
                u0 = emb[(size_t)nrow * DD + lane];
                u1 = emb[(size_t)nrow * DD + 64 + lane];
            } else {
                int s0 = so[kind], s1 = so[kind + 1];
                float a0 = 0.f, a1 = 0.f;
                for (int j = s0; j < s1; ++j) {
                    int sv = rb[j] & 2047;
                    int rw = nid[sv];
                    a0 += emb[(size_t)rw * DD + lane];
                    a1 += emb[(size_t)rw * DD + 64 + lane];
                }
                float inv = (s1 > s0) ? 1.f / (float)(s1 - s0) : 0.f;
                u0 = a0 * inv; u1 = a1 * inv;
            }
            Uc[row][s * DD + lane]      = u0;
            Uc[row][s * DD + 64 + lane] = u1;
        }
    }
    __syncthreads();

    // --- Phase B: GEMM. Wave w -> rows 4w..4w+3; lane -> cols 4*lane..4*lane+3
    int cg = lane;
    float4 acc0 = {0,0,0,0}, acc1 = {0,0,0,0}, acc2 = {0,0,0,0}, acc3 = {0,0,0,0};
    const float4* W2_4 = (const float4*)W2;
    int kbase = ks * SK;
    for (int c = 0; c < SK / KC; ++c) {
        __syncthreads();               // Wb consumed (and Uc ready at c=0)
        // stage Wb[32][256] from W2 rows kbase + c*32 ..
        for (int it = 0; it < KC * 256 / 4 / 256; ++it) {
            int fid = it * 256 + t;
            int kr = fid >> 6, col4 = fid & 63;
            ((float4*)Wb)[fid] = W2_4[(size_t)(kbase + c * KC + kr) * 64 + col4];
        }
        __syncthreads();
        int kb = c * KC;
#pragma unroll 4
        for (int kk = 0; kk < KC; ++kk) {
            float4 wv = ((const float4*)Wb[kk])[cg];
            float u0 = Uc[4 * w + 0][kb + kk];
            float u1 = Uc[4 * w + 1][kb + kk];
            float u2 = Uc[4 * w + 2][kb + kk];
            float u3 = Uc[4 * w + 3][kb + kk];
            fma4(acc0, u0, wv);
            fma4(acc1, u1, wv);
            fma4(acc2, u2, wv);
            fma4(acc3, u3, wv);
        }
    }
    // --- epilogue: write partials
    size_t base = ((size_t)ks * 3200 + m0 + 4 * w) * 256 + 4 * cg;
    *(float4*)(Xpart + base)           = acc0;
    *(float4*)(Xpart + base + 256)     = acc1;
    *(float4*)(Xpart + base + 512)     = acc2;
    *(float4*)(Xpart + base + 768)     = acc3;
}

// ---------------------------------------------------------------------------
// K4: attn_batch — one block (4 waves) per batch. Stage X (transposed) and XA
// from the 3 K-slice partials + bias2 in one pass; compute p/q in-block;
// softmax + pooled product in-wave; out[b] written directly.
// ---------------------------------------------------------------------------
__global__ __launch_bounds__(256) void attn_batch(const float* __restrict__ Xpart,
                                                  const float* __restrict__ bias2,
                                                  const float* __restrict__ va,
                                                  const float* __restrict__ vf,
                                                  const float* __restrict__ attn_b,
                                                  const float* __restrict__ fc_b,
                                                  float* __restrict__ out) {
    __shared__ float4 XT4[32][64];    // XT4[k][m] = X[m][4k..4k+3]; 32 KB
    __shared__ float4 XA4[LL][32];    // XA rows as float4; 25.6 KB
    __shared__ float pvs[64], qvs[64];
    __shared__ float4 va4[32], vf4[32];
    __shared__ float partial[4];

    int b = blockIdx.x, t = threadIdx.x;
    int w = t >> 6, lane = t & 63;

    const float4* bias4 = (const float4*)bias2;
    for (int idx = t; idx < LL * 64; idx += 256) {
        int row = idx >> 6, c4 = idx & 63;
        float4 v = bias4[c4];
        size_t p0 = ((size_t)b * LL + row) * 64 + c4;
#pragma unroll
        for (int ks = 0; ks < NS; ++ks) {
            float4 xp = ((const float4*)Xpart)[(size_t)ks * 3200 * 64 + p0];
            v.x += xp.x; v.y += xp.y; v.z += xp.z; v.w += xp.w;
        }
        if (c4 < 32) XT4[c4][row] = v;
        else         XA4[row][c4 - 32] = v;
    }
    if (t < 32) va4[t] = ((const float4*)va)[t];
    else if (t < 64) vf4[t - 32] = ((const float4*)vf)[t - 32];
    __syncthreads();

    // p/q: wave 0 -> p, wave 1 -> q (lane = row m)
    if (w == 0) {
        float s = 0.f;
        if (lane < LL) {
#pragma unroll
            for (int kk = 0; kk < 32; ++kk) {
                float4 x = XT4[kk][lane], vv = va4[kk];
                s = fmaf(x.x, vv.x, s); s = fmaf(x.y, vv.y, s);
                s = fmaf(x.z, vv.z, s); s = fmaf(x.w, vv.w, s);
            }
        }
        pvs[lane] = s;
    } else if (w == 1) {
        float s = 0.f;
        if (lane < LL) {
#pragma unroll
            for (int kk = 0; kk < 32; ++kk) {
                float4 x = XT4[kk][lane], vv = vf4[kk];
                s = fmaf(x.x, vv.x, s); s = fmaf(x.y, vv.y, s);
                s = fmaf(x.z, vv.z, s); s = fmaf(x.w, vv.w, s);
            }
        }
        qvs[lane] = s;
    }
    __syncthreads();

    const float scale = 0.07216878364870322f;  // 1/sqrt(192)
    float ab = attn_b[0];
    float local = 0.f;
    for (int l = w; l < LL; l += 4) {
        float s = 0.f;
#pragma unroll
        for (int kk = 0; kk < 32; ++kk) {
            float4 xa = XA4[l][kk];           // broadcast
            float4 xt = XT4[kk][lane];        // conflict-free b128
            s = fmaf(xa.x, xt.x, s);
            s = fmaf(xa.y, xt.y, s);
            s = fmaf(xa.z, xt.z, s);
            s = fmaf(xa.w, xt.w, s);
        }
        s *= scale;
        float sval = (lane < LL) ? s : -INFINITY;
        float mx = sval;
#pragma unroll
        for (int off = 32; off; off >>= 1) mx = fmaxf(mx, __shfl_xor(mx, off));
        float e = (lane < LL) ? __expf(sval - mx) : 0.f;
        float sum = e, pa = e * pvs[lane], qa = e * qvs[lane];
#pragma unroll
        for (int off = 32; off; off >>= 1) {
            sum += __shfl_xor(sum, off);
            pa  += __shfl_xor(pa, off);
            qa  += __shfl_xor(qa, off);
        }
        float inv = 1.f / sum;
        local += (pa * inv + ab) * (qa * inv);
    }
    if (lane == 0) partial[w] = local;
    __syncthreads();
    if (t == 0) {
        float s = partial[0] + partial[1] + partial[2] + partial[3];
        out[b] = 1.f / (1.f + expf(-(s + fc_b[0])));
    }
}

// ---------------------------------------------------------------------------
extern "C" void kernel_launch(void* const* d_in, const int* in_sizes, int n_in,
                              void* d_out, int out_size, void* d_ws, size_t ws_size,
                              hipStream_t stream) {
    const float* emb     = (const float*)d_in[0];
    const float* bases   = (const float*)d_in[1];
    const float* comp    = (const float*)d_in[2];
    const float* root_w  = (const float*)d_in[3];
    const float* root_b  = (const float*)d_in[4];
    const float* wq      = (const float*)d_in[5];
    const float* wk      = (const float*)d_in[6];
    const float* wv      = (const float*)d_in[7];
    const float* attn_w  = (const float*)d_in[8];
    const float* attn_b  = (const float*)d_in[9];
    const float* fc_w    = (const float*)d_in[10];
    const float* fc_b    = (const float*)d_in[11];
    const int* node_ids  = (const int*)d_in[12];
    const int* edge_index= (const int*)d_in[13];
    const int* edge_type = (const int*)d_in[14];
    const int* sent_ids  = (const int*)d_in[15];
    float* out = (float*)d_out;

    float* ws = (float*)d_ws;
    float* W2    = ws;                        // 768*256 = 196608
    float* A     = ws + 196608;               // 16384
    float* bias2 = ws + 212992;               // 256
    float* va    = ws + 213248;               // 128
    float* vf    = ws + 213376;               // 128
    float* Xpart = ws + 213504;               // 3*3200*256 = 2457600
    int* rep     = (int*)(ws + 2671104);      // 3200
    int* segoff  = (int*)(ws + 2674304);      // 64*251 = 16064
    int* recbuf2 = (int*)(ws + 2690368);      // 65536
    // total 2755904 floats ≈ 11.0 MiB

    hipLaunchKernelGGL(precompute_base, dim3(513), dim3(256), 0, stream,
                       bases, comp, root_w, root_b, wq, wk, wv, attn_w, fc_w,
                       W2, A, va, vf, bias2);
    hipLaunchKernelGGL(precompute_fold, dim3(769), dim3(128), 0, stream,
                       A, root_b, W2, bias2);
    hipLaunchKernelGGL(matchseg, dim3(BDIM), dim3(512), 0, stream,
                       edge_index, edge_type, sent_ids, rep, segoff, recbuf2);
    hipLaunchKernelGGL(gemm_ksplit, dim3(200 * NS), dim3(256), 0, stream,
                       emb, W2, node_ids, sent_ids, rep, segoff, recbuf2, Xpart);
    hipLaunchKernelGGL(attn_batch, dim3(BDIM), dim3(256), 0, stream,
                       Xpart, bias2, va, vf, attn_b, fc_b, out);
}